// Round 3
// baseline (246.014 us; speedup 1.0000x reference)
//
#include <hip/hip_runtime.h>
#include <hip/hip_bf16.h>
#include <cstddef>

// Problem dims (fixed): B=8, T=200, U=50, U1=51, H=320, V=1024.
#define Bdim 8
#define Tdim 200
#define Udim 50
#define U1dim 51
#define Hdim 320
#define Vdim 1024
#define NEGV -1.0e30f

using short8 = __attribute__((ext_vector_type(8))) short;
using f32x4  = __attribute__((ext_vector_type(4))) float;

static __device__ __forceinline__ ushort f2bf(float x) {
    __hip_bfloat16 h = __float2bfloat16(x);
    return *reinterpret_cast<ushort*>(&h);
}
static __device__ __forceinline__ int pack2(float a, float b) {
    return (int)f2bf(a) | ((int)f2bf(b) << 16);
}

// ---------------------------------------------------------------------------
// Fused-weight prep:  Wfe_t[v][j] = sum_p W_ff_enc[p][v] * W_enc[j][p]   (bf16 out)
//                     Wfp_t[v][j] = sum_p W_ff_pred[p][v] * W_pred[j][p]
//                     cvec[v] = b_enc @ W_ff_enc + b_ff ;  dvec[v] = b_pred @ W_ff_pred
// GEMM blocks: M=1024 (v), N=320 (j), K=320 (p). A = W_ff^T (transposed staging,
// f32->bf16), B = W (direct row-major staging, f32->bf16).
// grid (10, 17): x<5 enc, x>=5 pred; y==16 row = bias vectors.
// ---------------------------------------------------------------------------
__global__ __launch_bounds__(256) void fuse_weights(
    const float* __restrict__ W_enc, const float* __restrict__ W_ff_enc,
    const float* __restrict__ W_pred, const float* __restrict__ W_ff_pred,
    const float* __restrict__ b_enc, const float* __restrict__ b_pred,
    const float* __restrict__ b_ff,
    ushort* __restrict__ Wfe_t, ushort* __restrict__ Wfp_t,
    float* __restrict__ cvec, float* __restrict__ dvec)
{
    const int tid = threadIdx.x;
    if (blockIdx.y == 16) {                 // fused bias vectors
        if (blockIdx.x > 1) return;
        const bool e = (blockIdx.x == 0);
        const float* bv = e ? b_enc : b_pred;
        const float* Wf = e ? W_ff_enc : W_ff_pred;
        float* ovec = e ? cvec : dvec;
        const int v = tid * 4;
        float4 acc = make_float4(0.f, 0.f, 0.f, 0.f);
        for (int p = 0; p < Hdim; ++p) {
            float s = bv[p];
            float4 w = *(const float4*)&Wf[(size_t)p * Vdim + v];
            acc.x += s * w.x; acc.y += s * w.y; acc.z += s * w.z; acc.w += s * w.w;
        }
        if (e) {
            float4 bf = *(const float4*)&b_ff[v];
            acc.x += bf.x; acc.y += bf.y; acc.z += bf.z; acc.w += bf.w;
        }
        *(float4*)&ovec[v] = acc;
        return;
    }

    const bool e = (blockIdx.x < 5);
    const float* A  = e ? W_ff_enc : W_ff_pred;   // [320][1024] f32, used transposed
    const float* Bm = e ? W_enc    : W_pred;      // [320][320]  f32, direct
    ushort* Cout    = e ? Wfe_t    : Wfp_t;       // [1024][320] bf16
    const int n0 = (blockIdx.x % 5) * 64;         // j
    const int m0 = blockIdx.y * 64;               // v

    __shared__ short As[64][40];   // As[v][p]
    __shared__ short Bs[64][40];   // Bs[j][p]

    const int ar = tid >> 3;            // p row 0..31
    const int ac = (tid & 7) * 8;       // v base 0..56
    const int br = tid >> 2;            // j row 0..63
    const int bc = (tid & 3) * 8;       // p base 0..24

    const int lane = tid & 63;
    const int wave = tid >> 6;
    const int wr = wave >> 1, wc = wave & 1;
    const int lrow = lane & 15;
    const int kg = (lane >> 4) * 8;

    f32x4 acc[2][2] = {};

    for (int k0 = 0; k0 < Hdim; k0 += 32) {
        float4 a0 = *(const float4*)&A[(size_t)(k0 + ar) * Vdim + m0 + ac];
        float4 a1 = *(const float4*)&A[(size_t)(k0 + ar) * Vdim + m0 + ac + 4];
        As[ac + 0][ar] = (short)f2bf(a0.x);
        As[ac + 1][ar] = (short)f2bf(a0.y);
        As[ac + 2][ar] = (short)f2bf(a0.z);
        As[ac + 3][ar] = (short)f2bf(a0.w);
        As[ac + 4][ar] = (short)f2bf(a1.x);
        As[ac + 5][ar] = (short)f2bf(a1.y);
        As[ac + 6][ar] = (short)f2bf(a1.z);
        As[ac + 7][ar] = (short)f2bf(a1.w);
        float4 w0 = *(const float4*)&Bm[(size_t)(n0 + br) * Hdim + k0 + bc];
        float4 w1 = *(const float4*)&Bm[(size_t)(n0 + br) * Hdim + k0 + bc + 4];
        int4 bp = make_int4(pack2(w0.x, w0.y), pack2(w0.z, w0.w),
                            pack2(w1.x, w1.y), pack2(w1.z, w1.w));
        *(int4*)&Bs[br][bc] = bp;
        __syncthreads();

        short8 fa0 = *(const short8*)&As[wr * 32 + lrow][kg];
        short8 fa1 = *(const short8*)&As[wr * 32 + 16 + lrow][kg];
        short8 fb0 = *(const short8*)&Bs[wc * 32 + lrow][kg];
        short8 fb1 = *(const short8*)&Bs[wc * 32 + 16 + lrow][kg];
        acc[0][0] = __builtin_amdgcn_mfma_f32_16x16x32_bf16(fa0, fb0, acc[0][0], 0, 0, 0);
        acc[0][1] = __builtin_amdgcn_mfma_f32_16x16x32_bf16(fa0, fb1, acc[0][1], 0, 0, 0);
        acc[1][0] = __builtin_amdgcn_mfma_f32_16x16x32_bf16(fa1, fb0, acc[1][0], 0, 0, 0);
        acc[1][1] = __builtin_amdgcn_mfma_f32_16x16x32_bf16(fa1, fb1, acc[1][1], 0, 0, 0);
        __syncthreads();
    }

    // C/D: col = lane&15, row = (lane>>4)*4 + reg
    #pragma unroll
    for (int fm = 0; fm < 2; ++fm) {
        #pragma unroll
        for (int fn = 0; fn < 2; ++fn) {
            int col = n0 + wc * 32 + fn * 16 + lrow;
            int r0 = m0 + wr * 32 + fm * 16 + (lane >> 4) * 4;
            #pragma unroll
            for (int r = 0; r < 4; ++r)
                Cout[(size_t)(r0 + r) * Hdim + col] = f2bf(acc[fm][fn][r]);
        }
    }
}

// ---------------------------------------------------------------------------
// Main GEMM: rows = enc (1600) or pred (408) samples, N=1024, K=320.
// C[m][v] = sum_j A[m][j](f32->bf16 staged) * Wt[v][j] + vec[v]   -> f32
// grid (16, 32): y<25 enc, y>=25 pred.
// ---------------------------------------------------------------------------
__global__ __launch_bounds__(256) void main_gemm(
    const float* __restrict__ enc, const float* __restrict__ pred,
    const ushort* __restrict__ Wfe_t, const ushort* __restrict__ Wfp_t,
    const float* __restrict__ cvec, const float* __restrict__ dvec,
    float* __restrict__ enc_part, float* __restrict__ pred_part)
{
    const bool e = (blockIdx.y < 25);
    const float*  A    = e ? enc : pred;
    const ushort* Bt   = e ? Wfe_t : Wfp_t;
    const float*  bias = e ? cvec : dvec;
    float*        C    = e ? enc_part : pred_part;
    const int M  = e ? (Bdim * Tdim) : (Bdim * U1dim);
    const int m0 = (e ? blockIdx.y : blockIdx.y - 25) * 64;
    const int n0 = blockIdx.x * 64;

    __shared__ short As[64][40];
    __shared__ short Bs[64][40];
    const int tid = threadIdx.x;
    const int sr = tid >> 2;
    const int sc = (tid & 3) * 8;

    const int lane = tid & 63;
    const int wave = tid >> 6;
    const int wr = wave >> 1, wc = wave & 1;
    const int lrow = lane & 15;
    const int kg = (lane >> 4) * 8;

    f32x4 acc[2][2] = {};

    for (int k0 = 0; k0 < Hdim; k0 += 32) {
        int4 av = make_int4(0, 0, 0, 0);
        if (m0 + sr < M) {
            float4 x0 = *(const float4*)&A[(size_t)(m0 + sr) * Hdim + k0 + sc];
            float4 x1 = *(const float4*)&A[(size_t)(m0 + sr) * Hdim + k0 + sc + 4];
            av = make_int4(pack2(x0.x, x0.y), pack2(x0.z, x0.w),
                           pack2(x1.x, x1.y), pack2(x1.z, x1.w));
        }
        *(int4*)&As[sr][sc] = av;
        *(int4*)&Bs[sr][sc] = *(const int4*)&Bt[(size_t)(n0 + sr) * Hdim + k0 + sc];
        __syncthreads();

        short8 fa0 = *(const short8*)&As[wr * 32 + lrow][kg];
        short8 fa1 = *(const short8*)&As[wr * 32 + 16 + lrow][kg];
        short8 fb0 = *(const short8*)&Bs[wc * 32 + lrow][kg];
        short8 fb1 = *(const short8*)&Bs[wc * 32 + 16 + lrow][kg];
        acc[0][0] = __builtin_amdgcn_mfma_f32_16x16x32_bf16(fa0, fb0, acc[0][0], 0, 0, 0);
        acc[0][1] = __builtin_amdgcn_mfma_f32_16x16x32_bf16(fa0, fb1, acc[0][1], 0, 0, 0);
        acc[1][0] = __builtin_amdgcn_mfma_f32_16x16x32_bf16(fa1, fb0, acc[1][0], 0, 0, 0);
        acc[1][1] = __builtin_amdgcn_mfma_f32_16x16x32_bf16(fa1, fb1, acc[1][1], 0, 0, 0);
        __syncthreads();
    }

    #pragma unroll
    for (int fm = 0; fm < 2; ++fm) {
        #pragma unroll
        for (int fn = 0; fn < 2; ++fn) {
            int col = n0 + wc * 32 + fn * 16 + lrow;
            int r0 = m0 + wr * 32 + fm * 16 + (lane >> 4) * 4;
            float bv = bias[col];
            #pragma unroll
            for (int r = 0; r < 4; ++r) {
                int row = r0 + r;
                if (row < M)
                    C[(size_t)row * Vdim + col] = acc[fm][fn][r] + bv;
            }
        }
    }
}

// ---------------------------------------------------------------------------
// Joint + fused log-softmax stats. Block = (b,t); 4 waves stride over u.
// Lane owns v = lane*16..lane*16+15, all in registers (no LDS).
// Aligned split stores around the off-by-one-float output base.
// ---------------------------------------------------------------------------
__global__ __launch_bounds__(256) void joint_lse(
    const float* __restrict__ enc_part, const float* __restrict__ pred_part,
    const int* __restrict__ ys, float* __restrict__ out,
    float* __restrict__ lp_blank, float* __restrict__ lp_label)
{
    const int bt = blockIdx.x;       // b*T + t
    const int b = bt / Tdim;
    const int tid = threadIdx.x;
    const int lane = tid & 63;
    const int wave = tid >> 6;
    if (bt == 0 && tid == 0) out[0] = 0.f;   // loss accumulator (alpha atomicAdds)

    const float* Erow = enc_part + (size_t)bt * Vdim + lane * 16;
    float4 e0 = *(const float4*)(Erow + 0);
    float4 e1 = *(const float4*)(Erow + 4);
    float4 e2 = *(const float4*)(Erow + 8);
    float4 e3 = *(const float4*)(Erow + 12);

    float* logits = out + 1;

    for (int u = wave; u < U1dim; u += 4) {
        const float* P = pred_part + (size_t)(b * U1dim + u) * Vdim + lane * 16;
        float4 p0 = *(const float4*)(P + 0);
        float4 p1 = *(const float4*)(P + 4);
        float4 p2 = *(const float4*)(P + 8);
        float4 p3 = *(const float4*)(P + 12);
        float xa[16];
        xa[0]=e0.x+p0.x;  xa[1]=e0.y+p0.y;  xa[2]=e0.z+p0.z;  xa[3]=e0.w+p0.w;
        xa[4]=e1.x+p1.x;  xa[5]=e1.y+p1.y;  xa[6]=e1.z+p1.z;  xa[7]=e1.w+p1.w;
        xa[8]=e2.x+p2.x;  xa[9]=e2.y+p2.y;  xa[10]=e2.z+p2.z; xa[11]=e2.w+p2.w;
        xa[12]=e3.x+p3.x; xa[13]=e3.y+p3.y; xa[14]=e3.z+p3.z; xa[15]=e3.w+p3.w;

        float* L = logits + (size_t)bt * U1dim * Vdim + (size_t)u * Vdim + lane * 16;
        L[0] = xa[0]; L[1] = xa[1]; L[2] = xa[2];
        *(float4*)(L + 3)  = make_float4(xa[3],  xa[4],  xa[5],  xa[6]);
        *(float4*)(L + 7)  = make_float4(xa[7],  xa[8],  xa[9],  xa[10]);
        *(float4*)(L + 11) = make_float4(xa[11], xa[12], xa[13], xa[14]);
        L[15] = xa[15];

        float m = xa[0];
        #pragma unroll
        for (int i = 1; i < 16; ++i) m = fmaxf(m, xa[i]);
        #pragma unroll
        for (int off = 32; off >= 1; off >>= 1) m = fmaxf(m, __shfl_xor(m, off));
        float s = 0.f;
        #pragma unroll
        for (int i = 0; i < 16; ++i) s += __expf(xa[i] - m);
        #pragma unroll
        for (int off = 32; off >= 1; off >>= 1) s += __shfl_xor(s, off);
        float lse = m + __logf(s);

        int vlab = (u < Udim) ? ys[b * Udim + u] : 0;
        int idx = vlab & 15;
        int src = vlab >> 4;
        float cand = xa[0];
        #pragma unroll
        for (int i = 1; i < 16; ++i) if (i == idx) cand = xa[i];
        float lab = __shfl(cand, src);
        float l0 = __shfl(xa[0], 0);

        if (lane == 0) {
            lp_blank[(size_t)bt * U1dim + u] = l0 - lse;
            if (u < Udim) lp_label[(size_t)bt * Udim + u] = lab - lse;
        }
    }
}

// ---------------------------------------------------------------------------
// RNN-T alpha wavefront over anti-diagonals; one block per batch element.
// Folds the mean: atomicAdd(-loss/B) into out[0] (zeroed by joint_lse).
// ---------------------------------------------------------------------------
__global__ __launch_bounds__(256) void alpha_kernel(
    const float* __restrict__ lp_blank, const float* __restrict__ lp_label,
    const int* __restrict__ ylen, float* __restrict__ out)
{
    __shared__ float s_bl[U1dim * Tdim];   // [u][t]
    __shared__ float s_lab[Udim * Tdim];   // [u][t]
    const int b = blockIdx.x;
    const int tid = threadIdx.x;
    const float* gb = lp_blank + (size_t)b * Tdim * U1dim;
    const float* gl = lp_label + (size_t)b * Tdim * Udim;
    for (int i = tid; i < Tdim * U1dim; i += 256) {
        int t = i / U1dim, u = i % U1dim;
        s_bl[u * Tdim + t] = gb[i];
    }
    for (int i = tid; i < Tdim * Udim; i += 256) {
        int t = i / Udim, u = i % Udim;
        s_lab[u * Tdim + t] = gl[i];
    }
    __syncthreads();

    if (tid < 64) {
        const int u = tid;
        float cur = NEGV;
        for (int d = 0; d < Tdim + U1dim - 1; ++d) {
            float left = __shfl_up(cur, 1);
            int t = d - u;
            if (u < U1dim && t >= 0 && t < Tdim) {
                float h = (t >= 1) ? cur + s_bl[u * Tdim + (t - 1)] : NEGV;
                float g = (u >= 1) ? left + s_lab[(u - 1) * Tdim + t] : NEGV;
                float mx = fmaxf(h, g);
                float nv = mx + log1pf(__expf(-fabsf(h - g)));
                if (d == 0) nv = 0.f;
                cur = nv;
            }
        }
        const int L = ylen[b];
        if (u == L)
            atomicAdd(out, -(cur + s_bl[L * Tdim + (Tdim - 1)]) * (1.0f / Bdim));
    }
}

// ---------------------------------------------------------------------------
extern "C" void kernel_launch(void* const* d_in, const int* in_sizes, int n_in,
                              void* d_out, int out_size, void* d_ws, size_t ws_size,
                              hipStream_t stream)
{
    const float* enc      = (const float*)d_in[0];   // (8,200,320)
    const float* pred     = (const float*)d_in[1];   // (8,51,320)
    const int*   ys       = (const int*)d_in[4];     // (8,50)
    const int*   ylen     = (const int*)d_in[5];     // (8,)
    const float* W_enc    = (const float*)d_in[6];   // (320,320)
    const float* b_enc    = (const float*)d_in[7];   // (320,)
    const float* W_pred   = (const float*)d_in[8];
    const float* b_pred   = (const float*)d_in[9];
    const float* W_ff_enc = (const float*)d_in[10];  // (320,1024)
    const float* W_ff_pred= (const float*)d_in[11];
    const float* b_ff     = (const float*)d_in[12];  // (1024,)
    float* out = (float*)d_out;
    char* ws = (char*)d_ws;

    // -------- workspace layout (byte offsets) --------
    float*  enc_part  = (float*) (ws + 0);          // 1600*1024 f32 = 6,553,600 B
    float*  pred_part = (float*) (ws + 6553600);    //  408*1024 f32 = 1,671,168 B
    ushort* Wfe_t     = (ushort*)(ws + 8224768);    // 1024*320 bf16 =   655,360 B
    ushort* Wfp_t     = (ushort*)(ws + 8880128);    //   655,360 B
    float*  cvec      = (float*) (ws + 9535488);    //     4,096 B
    float*  dvec      = (float*) (ws + 9539584);    //     4,096 B
    float*  lp_blank  = (float*) (ws + 9543680);    //   326,400 B
    float*  lp_label  = (float*) (ws + 9870080);    //   320,000 B  (end 10,190,080)

    dim3 blk(256);
    fuse_weights<<<dim3(10, 17), blk, 0, stream>>>(
        W_enc, W_ff_enc, W_pred, W_ff_pred, b_enc, b_pred, b_ff,
        Wfe_t, Wfp_t, cvec, dvec);
    main_gemm<<<dim3(16, 32), blk, 0, stream>>>(
        enc, pred, Wfe_t, Wfp_t, cvec, dvec, enc_part, pred_part);
    joint_lse<<<dim3(Bdim * Tdim), blk, 0, stream>>>(
        enc_part, pred_part, ys, out, lp_blank, lp_label);
    alpha_kernel<<<dim3(Bdim), blk, 0, stream>>>(lp_blank, lp_label, ylen, out);
}